// Round 8
// baseline (5922.678 us; speedup 1.0000x reference)
//
#include <hip/hip_runtime.h>
#include <float.h>

#define N_PTS 16384
#define M_PTS 4096
#define K_NN  16
#define CIN   64
#define COUT  64

typedef float v2f __attribute__((ext_vector_type(2)));
typedef unsigned long long ull;

// Exact f32 rounding to match numpy/jax: ((dx*dx + dy*dy) + dz*dz), no fma contraction.
__device__ __forceinline__ float dist2_exact(float ax, float ay, float az,
                                             float bx, float by, float bz) {
    float dx = __fsub_rn(ax, bx);
    float dy = __fsub_rn(ay, by);
    float dz = __fsub_rn(az, bz);
    return __fadd_rn(__fadd_rn(__fmul_rn(dx, dx), __fmul_rn(dy, dy)), __fmul_rn(dz, dz));
}

// Packed f32 ops via inline asm (v2f codegen otherwise scalarizes — R6 evidence).
__device__ __forceinline__ v2f pk_add(v2f a, v2f b) {
    v2f d; asm("v_pk_add_f32 %0, %1, %2" : "=v"(d) : "v"(a), "v"(b)); return d;
}
__device__ __forceinline__ v2f pk_mul(v2f a, v2f b) {
    v2f d; asm("v_pk_mul_f32 %0, %1, %2" : "=v"(d) : "v"(a), "v"(b)); return d;
}

// ---- DPP wave-64 max-reduction step carrying a 3-float payload (R24) ----
// Moves {key(2dw), x, y, z} from the DPP-source lane and cndmask-selects the
// 5-dword tuple as a unit on key>cur. Idempotent max -> full masks safe.
template <int CTRL>
__device__ __forceinline__ void dpp_pay_step(ull& k, float& x, float& y, float& z) {
    const int lo = (int)(unsigned)k, hi = (int)(unsigned)(k >> 32);
    const unsigned nlo = (unsigned)__builtin_amdgcn_update_dpp(lo, lo, CTRL, 0xf, 0xf, false);
    const unsigned nhi = (unsigned)__builtin_amdgcn_update_dpp(hi, hi, CTRL, 0xf, 0xf, false);
    const int xi = __float_as_int(x), yi = __float_as_int(y), zi = __float_as_int(z);
    const int nx = __builtin_amdgcn_update_dpp(xi, xi, CTRL, 0xf, 0xf, false);
    const int ny = __builtin_amdgcn_update_dpp(yi, yi, CTRL, 0xf, 0xf, false);
    const int nz = __builtin_amdgcn_update_dpp(zi, zi, CTRL, 0xf, 0xf, false);
    const ull nk = ((ull)nhi << 32) | (ull)nlo;
    if (nk > k) {
        k = nk;
        x = __int_as_float(nx); y = __int_as_float(ny); z = __int_as_float(nz);
    }
}

// Per-wave record extraction (R24): 6 payload-DPP steps -> lane 63 holds the
// wave's (max d2, min orig) element WITH its coordinates; 5 readlanes park the
// record in SGPRs. Key = d2_bits<<32 | ~orig — same ordering as R1 -> the pick
// sequence is bit-identical. No ballot/ctz/LDS anywhere on this path.
#define EXTRACT_RECORD()                                                          \
    {                                                                             \
        ull _k = bk; float _x = bx, _y = by, _z = bz;                             \
        dpp_pay_step<0x111>(_k, _x, _y, _z);                                      \
        dpp_pay_step<0x112>(_k, _x, _y, _z);                                      \
        dpp_pay_step<0x114>(_k, _x, _y, _z);                                      \
        dpp_pay_step<0x118>(_k, _x, _y, _z);                                      \
        dpp_pay_step<0x142>(_k, _x, _y, _z);                                      \
        dpp_pay_step<0x143>(_k, _x, _y, _z);                                      \
        my_klo = (unsigned)__builtin_amdgcn_readlane((int)(unsigned)_k, 63);      \
        my_khi = (unsigned)__builtin_amdgcn_readlane((int)(unsigned)(_k >> 32), 63); \
        my_wval = __int_as_float((int)my_khi);                                    \
        my_qx = __int_as_float(__builtin_amdgcn_readlane(__float_as_int(_x), 63)); \
        my_qy = __int_as_float(__builtin_amdgcn_readlane(__float_as_int(_y), 63)); \
        my_qz = __int_as_float(__builtin_amdgcn_readlane(__float_as_int(_z), 63)); \
    }

// ---------------------------------------------------------------------------
// Kernel 1: furthest point sampling. R24: single barrier per iteration,
// payload-carrying DPP reduces. All waves redundantly reduce the 16 records
// (cheap: 1 LDS read + 4 payload steps + 3 readlanes) — no second barrier,
// no s_win round-trip, no sortpos decode, no dependent coordinate fetch
// (R6 evidence: VALUBusy 0.22->0.13 with flat dur => latency-chain-bound).
// Records double-buffered (single-barrier safety). Register budget <64 by
// design (R2/R3: allocator caps at 64 VGPRs and spills past it).
// ---------------------------------------------------------------------------
__global__ __launch_bounds__(1024) void fps_kernel(const float* __restrict__ p,
                                                   float* __restrict__ out) {
#pragma clang fp contract(off)
    const int t = threadIdx.x;
    const int lane = t & 63, wv = t >> 6;
    __shared__ char smem[147456];                      // keys[16384] then s_xy4[1024*9]
    __shared__ float s_pick[1024 * 3];                 // pick ring (12 KB)
    __shared__ ull s_rec[2][16];                       // record keys (dbuf)
    __shared__ float4 s_rxyz[2][16];                   // record coords (dbuf)

    ull* keys = (ull*)smem;
    float4* s_xy4 = (float4*)smem;                     // reuses keys region (144 KB)

    // ---- Phase A: bitonic sort by x (keys unique via idx bits) ----
    for (int u = 0; u < 16; ++u) {
        const int j = u * 1024 + t;
        keys[j] = ((ull)__float_as_uint(p[3 * j]) << 32) | (unsigned)j;
    }
    __syncthreads();
    for (int k = 2; k <= N_PTS; k <<= 1) {
        for (int j = k >> 1; j > 0; j >>= 1) {
            for (int e = 0; e < 8; ++e) {
                const int c = e * 1024 + t;
                const int i1 = 2 * c - (c & (j - 1));
                const int i2 = i1 + j;
                const ull a = keys[i1], b = keys[i2];
                const bool up = ((i1 & k) == 0);
                if ((a > b) == up) { keys[i1] = b; keys[i2] = a; }
            }
            __syncthreads();
        }
    }

    // read own 16 sorted keys -> packed original indices (8 regs)
    unsigned opk[8];
#pragma unroll
    for (int u = 0; u < 8; ++u) {
        const ull a = keys[t * 16 + 2 * u];
        const ull b = keys[t * 16 + 2 * u + 1];
        opk[u] = ((unsigned)a & 0xffffu) | (((unsigned)b & 0xffffu) << 16);
    }
    __syncthreads();                                   // all key reads done before overwrite

    // ---- gather coords: LDS xy ({x0,x1,y0,y1}) + reg z/d2, init payload ----
    v2f zp[8], d2[8];
    const float q0x = p[0], q0y = p[1], q0z = p[2];
    ull bk = 0;
    float bx = 0.0f, by = 0.0f, bz = 0.0f;
    float xf = 0.0f, xl = 0.0f;
#pragma unroll
    for (int u = 0; u < 8; ++u) {
        const int o0 = (int)(opk[u] & 0xffffu), o1 = (int)(opk[u] >> 16);
        const float x0 = p[3 * o0], y0 = p[3 * o0 + 1], z0 = p[3 * o0 + 2];
        const float x1 = p[3 * o1], y1 = p[3 * o1 + 1], z1 = p[3 * o1 + 2];
        s_xy4[t * 9 + u] = make_float4(x0, x1, y0, y1);
        zp[u] = (v2f){z0, z1};
        d2[u] = (v2f){dist2_exact(x0, y0, z0, q0x, q0y, q0z),
                      dist2_exact(x1, y1, z1, q0x, q0y, q0z)};
        const ull ka = ((ull)__float_as_uint(d2[u].x) << 32) | (ull)(~(unsigned)o0);
        const ull kb = ((ull)__float_as_uint(d2[u].y) << 32) | (ull)(~(unsigned)o1);
        if (ka > bk) { bk = ka; bx = x0; by = y0; bz = z0; }
        if (kb > bk) { bk = kb; bx = x1; by = y1; bz = z1; }
        if (u == 0) xf = x0;
        if (u == 7) xl = x1;
    }
    const float wxmin = __int_as_float(__builtin_amdgcn_readlane(__float_as_int(xf), 0));
    const float wxmax = __int_as_float(__builtin_amdgcn_readlane(__float_as_int(xl), 63));
    const float cx = 0.5f * (wxmin + wxmax);
    const float hw_safe = 0.5f * (wxmax - wxmin) + 1e-5f;

    float my_wval, my_qx, my_qy, my_qz;
    unsigned my_klo, my_khi;
    EXTRACT_RECORD();
    if (lane == 0) {
        s_rec[1][wv] = ((ull)my_khi << 32) | (ull)my_klo;
        s_rxyz[1][wv] = make_float4(my_qx, my_qy, my_qz, 0.0f);
    }
    if (t == 0) { s_pick[0] = q0x; s_pick[1] = q0y; s_pick[2] = q0z; }

    for (int i = 1; i < M_PTS; ++i) {
        const int par = i & 1;
        __syncthreads();                               // the ONE barrier per iteration

        // ring flush: once per 512 iters, previous 512-block (other ring half)
        if ((i & 511) == 0) {
            const int b = (i - 512) & 1023;
            const int base3 = (i - 512) * 3;
            out[base3 + t] = s_pick[b * 3 + t];
            if (t < 512) out[base3 + 1024 + t] = s_pick[b * 3 + 1024 + t];
        }

        // global winner: payload reduce over the 16 records — coords arrive
        // with the key; no ballot, no dependent LDS fetch.
        const int r = lane & 15;
        ull wk = s_rec[par][r];
        const float4 w4 = s_rxyz[par][r];
        float wx = w4.x, wy = w4.y, wz = w4.z;
        dpp_pay_step<0x111>(wk, wx, wy, wz);
        dpp_pay_step<0x112>(wk, wx, wy, wz);
        dpp_pay_step<0x114>(wk, wx, wy, wz);
        dpp_pay_step<0x118>(wk, wx, wy, wz);
        const float qx = __int_as_float(__builtin_amdgcn_readlane(__float_as_int(wx), 63));
        const float qy = __int_as_float(__builtin_amdgcn_readlane(__float_as_int(wy), 63));
        const float qz = __int_as_float(__builtin_amdgcn_readlane(__float_as_int(wz), 63));
        if (t == 0) {
            const int s3 = (i & 1023) * 3;
            s_pick[s3] = qx; s_pick[s3 + 1] = qy; s_pick[s3 + 2] = qz;
        }

        // ---- wave-level slab prune: skip update iff provably all no-ops ----
        const float dxq = fabsf(qx - cx);
        bool active = true;
        if (dxq > hw_safe) {
            const float lb = dxq - hw_safe;            // conservative lower bound
            active = (lb * lb <= my_wval);
        }
        if (active) {
            const v2f nqx2 = (v2f){-qx, -qx};
            const v2f nqy2 = (v2f){-qy, -qy};
            const v2f nqz2 = (v2f){-qz, -qz};
            bk = 0; bx = 0.0f; by = 0.0f; bz = 0.0f;
#pragma unroll
            for (int u = 0; u < 8; ++u) {
                const float4 xyu = s_xy4[t * 9 + u];
                const v2f xp = (v2f){xyu.x, xyu.y};    // {x0,x1}
                const v2f yp = (v2f){xyu.z, xyu.w};    // {y0,y1}
                const v2f dx = pk_add(xp, nqx2);       // exact x - qx
                const v2f dy = pk_add(yp, nqy2);
                const v2f dz = pk_add(zp[u], nqz2);
                const v2f m1 = pk_mul(dx, dx);
                const v2f m2 = pk_mul(dy, dy);
                const v2f m3 = pk_mul(dz, dz);
                const v2f s = pk_add(pk_add(m1, m2), m3);  // ((x²+y²)+z²) exact order
                d2[u] = __builtin_elementwise_min(d2[u], s);
                const unsigned o0 = opk[u] & 0xffffu, o1 = opk[u] >> 16;
                const ull ka = ((ull)__float_as_uint(d2[u].x) << 32) | (ull)(~o0);
                const ull kb = ((ull)__float_as_uint(d2[u].y) << 32) | (ull)(~o1);
                if (ka > bk) { bk = ka; bx = xyu.x; by = xyu.z; bz = zp[u].x; }
                if (kb > bk) { bk = kb; bx = xyu.y; by = xyu.w; bz = zp[u].y; }
            }
            EXTRACT_RECORD();                          // refresh record (SGPRs)
        }
        if (lane == 0) {
            s_rec[1 - par][wv] = ((ull)my_khi << 32) | (ull)my_klo;
            s_rxyz[1 - par][wv] = make_float4(my_qx, my_qy, my_qz, 0.0f);
        }
    }

    // final flush: picks 3584..4095 (ring half b=512) + n_o scalar
    __syncthreads();
    {
        const int base3 = 3584 * 3;
        const int b3 = 512 * 3;
        out[base3 + t] = s_pick[b3 + t];
        if (t < 512) out[base3 + 1024 + t] = s_pick[b3 + 1024 + t];
        if (t == 0) out[12288 + 786432] = 4096.0f;
    }
}

// ---------------------------------------------------------------------------
// Kernel 2 (R16): fused knn + vn. knn unchanged (bit-exactness). vn k-split:
// stage k=[0,8) for ALL 16 queries (96 KB), compute with all 1024 threads
// (thread = (qi,o), 16x64), then k=[8,16). Per-k leaky-ReLU makes k-split
// accumulation exact. Halves vn wall-time vs R15's half-idle 2-round form.
// ---------------------------------------------------------------------------
__global__ __launch_bounds__(1024)
void knnvn_kernel(const float* __restrict__ p, const float* __restrict__ x,
                  const float* __restrict__ Wf, const float* __restrict__ Wd,
                  float* __restrict__ out) {
    __shared__ __align__(16) char SMEM[133120];
    float* sWf = (float*)SMEM;                         // 16 KB  [c*64+o]
    float* sWd = (float*)(SMEM + 16384);               // 16 KB
    float* sg  = (float*)(SMEM + 32768);               // 96 KB  16 q x 8 k x 192
    int*  s_nn = (int*)(SMEM + 131072);                // 1 KB   16 q x 16

    const int t = threadIdx.x;
    const int lane = t & 63, wv = t >> 6;
    const int qbase = (int)blockIdx.x * 16;            // 256 blocks x 16 = 4096

    for (int u = t; u < CIN * COUT; u += 1024) {
        const int o = u >> 6, c = u & 63;
        sWf[c * 64 + o] = Wf[u];
        sWd[c * 64 + o] = Wd[u];
    }

    // ---- knn: one wave per query, results into LDS (exact top_k semantics) ----
    {
        const int m = qbase + wv;
        const float qx = out[3 * m], qy = out[3 * m + 1], qz = out[3 * m + 2];
        const float qq2 = __fadd_rn(__fadd_rn(__fmul_rn(qx, qx), __fmul_rn(qy, qy)),
                                    __fmul_rn(qz, qz));
        float D[16]; int I[16];
#pragma unroll
        for (int s = 0; s < 16; ++s) { D[s] = FLT_MAX; I[s] = 0x7fffffff; }
        for (int c = 0; c < N_PTS / 64; ++c) {
            const int j = c * 64 + lane;
            const float px = p[3 * j], py = p[3 * j + 1], pz = p[3 * j + 2];
            const float pp = __fadd_rn(__fadd_rn(__fmul_rn(px, px), __fmul_rn(py, py)),
                                       __fmul_rn(pz, pz));
            const float qp = __fadd_rn(__fadd_rn(__fmul_rn(qx, px), __fmul_rn(qy, py)),
                                       __fmul_rn(qz, pz));
            const float d = __fadd_rn(__fsub_rn(qq2, __fmul_rn(2.0f, qp)), pp);
            if (d < D[15]) {
                D[15] = d; I[15] = j;
#pragma unroll
                for (int s = 15; s > 0; --s) {
                    if (D[s] < D[s - 1]) {
                        float tf = D[s]; D[s] = D[s - 1]; D[s - 1] = tf;
                        int   ti = I[s]; I[s] = I[s - 1]; I[s - 1] = ti;
                    }
                }
            }
        }
        int myout = 0;
        for (int r = 0; r < 16; ++r) {
            float v = D[0]; int ix = I[0]; int bl = lane;
#pragma unroll
            for (int off = 1; off < 64; off <<= 1) {
                float ov = __shfl_xor(v, off);
                int   oi = __shfl_xor(ix, off);
                int   ol = __shfl_xor(bl, off);
                if (ov < v || (ov == v && oi < ix)) { v = ov; ix = oi; bl = ol; }
            }
            if (lane == bl) {
#pragma unroll
                for (int s = 0; s < 15; ++s) { D[s] = D[s + 1]; I[s] = I[s + 1]; }
                D[15] = FLT_MAX; I[15] = 0x7fffffff;
            }
            if (lane == r) myout = ix;
        }
        if (lane < K_NN) s_nn[wv * K_NN + lane] = myout;
    }

    // ---- vn, k-split: all 1024 threads = (qi 0..15, o 0..63) ----
    const int qi = t >> 6, o = t & 63;
    float a0 = 0.0f, a1 = 0.0f, a2 = 0.0f;
#pragma unroll
    for (int half = 0; half < 2; ++half) {
        __syncthreads();                               // nn ready / sg reuse safe
        // stage k in [half*8, half*8+8) for all 16 queries: 24576 floats
        for (int idx = t; idx < 16 * 8 * 192; idx += 1024) {
            const int pair = idx / 192;                // qj*8 + kk
            const int c3 = idx - pair * 192;
            const int jn = s_nn[(pair >> 3) * K_NN + half * 8 + (pair & 7)];
            sg[idx] = x[jn * 192 + c3];
        }
        __syncthreads();
        for (int kk = 0; kk < 8; ++kk) {
            const float* gk = &sg[(qi * 8 + kk) * 192];
            float q0 = 0.0f, q1 = 0.0f, q2 = 0.0f;
            float d0 = 0.0f, d1 = 0.0f, d2v = 0.0f;
#pragma unroll 8
            for (int c = 0; c < CIN; ++c) {
                const float wf = sWf[c * 64 + o];
                const float wd = sWd[c * 64 + o];
                const float g0 = gk[c * 3], g1 = gk[c * 3 + 1], g2 = gk[c * 3 + 2];
                q0 = fmaf(wf, g0, q0); q1 = fmaf(wf, g1, q1); q2 = fmaf(wf, g2, q2);
                d0 = fmaf(wd, g0, d0); d1 = fmaf(wd, g1, d1); d2v = fmaf(wd, g2, d2v);
            }
            const float dot = q0 * d0 + q1 * d1 + q2 * d2v;
            const float dns = d0 * d0 + d1 * d1 + d2v * d2v + 1e-6f;
            const float f = (dot >= 0.0f) ? 0.0f : 0.8f * (dot / dns);
            a0 += q0 - f * d0;
            a1 += q1 - f * d1;
            a2 += q2 - f * d2v;
        }
    }
    float* xo = out + 12288;
    const int m = qbase + qi;
    xo[(o * 3 + 0) * M_PTS + m] = a0 * 0.0625f;        // mean over 16
    xo[(o * 3 + 1) * M_PTS + m] = a1 * 0.0625f;
    xo[(o * 3 + 2) * M_PTS + m] = a2 * 0.0625f;
}

// ---------------------------------------------------------------------------
extern "C" void kernel_launch(void* const* d_in, const int* in_sizes, int n_in,
                              void* d_out, int out_size, void* d_ws, size_t ws_size,
                              hipStream_t stream) {
    const float* p  = (const float*)d_in[0];
    const float* x  = (const float*)d_in[1];
    const float* Wf = (const float*)d_in[2];
    const float* Wd = (const float*)d_in[3];
    float* out = (float*)d_out;

    fps_kernel<<<1, 1024, 0, stream>>>(p, out);
    knnvn_kernel<<<256, 1024, 0, stream>>>(p, x, Wf, Wd, out);
}

// Round 9
// 4571.556 us; speedup vs baseline: 1.2955x; 1.2955x over previous
//
#include <hip/hip_runtime.h>
#include <float.h>

#define N_PTS 16384
#define M_PTS 4096
#define K_NN  16
#define CIN   64
#define COUT  64

typedef float v2f __attribute__((ext_vector_type(2)));
typedef unsigned long long ull;

// Exact f32 rounding to match numpy/jax: ((dx*dx + dy*dy) + dz*dz), no fma contraction.
__device__ __forceinline__ float dist2_exact(float ax, float ay, float az,
                                             float bx, float by, float bz) {
    float dx = __fsub_rn(ax, bx);
    float dy = __fsub_rn(ay, by);
    float dz = __fsub_rn(az, bz);
    return __fadd_rn(__fadd_rn(__fmul_rn(dx, dx), __fmul_rn(dy, dy)), __fmul_rn(dz, dz));
}

// Packed f32 ops via inline asm (v2f codegen otherwise scalarizes — R6 evidence).
__device__ __forceinline__ v2f pk_add(v2f a, v2f b) {
    v2f d; asm("v_pk_add_f32 %0, %1, %2" : "=v"(d) : "v"(a), "v"(b)); return d;
}
__device__ __forceinline__ v2f pk_mul(v2f a, v2f b) {
    v2f d; asm("v_pk_mul_f32 %0, %1, %2" : "=v"(d) : "v"(a), "v"(b)); return d;
}

// ---- DPP wave-64 reduction step for packed u64 keys (idempotent max) ----
template <int CTRL>
__device__ __forceinline__ ull dpp_u64max_step(ull x) {
    int lo = (int)(unsigned)x;
    int hi = (int)(unsigned)(x >> 32);
    unsigned olo = (unsigned)__builtin_amdgcn_update_dpp(lo, lo, CTRL, 0xf, 0xf, false);
    unsigned ohi = (unsigned)__builtin_amdgcn_update_dpp(hi, hi, CTRL, 0xf, 0xf, false);
    ull o = ((ull)ohi << 32) | (ull)olo;
    return o > x ? o : x;
}
__device__ __forceinline__ ull umax64(ull a, ull b) { return a > b ? a : b; }

// Compile-time-indexed 8-way select (uniform _sh -> cndmask tree, no scratch).
#define SEL8(arr)                                                                 \
    ((_sh & 4) ? ((_sh & 2) ? ((_sh & 1) ? arr[7] : arr[6])                       \
                            : ((_sh & 1) ? arr[5] : arr[4]))                      \
               : ((_sh & 2) ? ((_sh & 1) ? arr[3] : arr[2])                       \
                            : ((_sh & 1) ? arr[1] : arr[0])))

// Per-wave record extraction (R21): key = d2_bits<<32 | ((orig^0x3fff)<<14 | sortpos).
// u64-max == (argmax d2, tie-break min orig) — bit-identical winner selection to
// R1 (orig is unique and fits 14 bits, so sortpos never decides). sortpos encodes
// the owning thread, so NO ballot/ctz: candidate z comes from the owner lane's zp
// regs ((klo>>4)&63 within this wave) via uniform cndmask tree + one readlane.
#define EXTRACT_RECORD()                                                          \
    {                                                                             \
        ull _r = bk;                                                              \
        _r = dpp_u64max_step<0x111>(_r);                                          \
        _r = dpp_u64max_step<0x112>(_r);                                          \
        _r = dpp_u64max_step<0x114>(_r);                                          \
        _r = dpp_u64max_step<0x118>(_r);                                          \
        _r = dpp_u64max_step<0x142>(_r);                                          \
        _r = dpp_u64max_step<0x143>(_r);                                          \
        my_klo = (unsigned)__builtin_amdgcn_readlane((int)(unsigned)_r, 63);      \
        my_khi = (unsigned)__builtin_amdgcn_readlane((int)(unsigned)(_r >> 32), 63); \
        my_wval = __int_as_float((int)my_khi);                                    \
        const int _hl = (int)((my_klo >> 4) & 63u);    /* owner lane (own wave) */ \
        const int _slot = (int)(my_klo & 15u);                                    \
        const int _sh = _slot >> 1;                                              \
        v2f _za = SEL8(zp);                                                       \
        const float _zc = (_slot & 1) ? _za.y : _za.x;                            \
        my_qz = __int_as_float(__builtin_amdgcn_readlane(__float_as_int(_zc), _hl)); \
    }

// ---------------------------------------------------------------------------
// Kernel 1: furthest point sampling — R21 VERBATIM (best measured: 4200 µs,
// Round 5). R24's payload-carrying reduce regressed (+1.3 ms: VGPR cap hit,
// 2x issue in update loop) — reverted. Register budget <64 by design
// (R2/R3: allocator caps at 64 VGPRs and spills past it).
// ---------------------------------------------------------------------------
__global__ __launch_bounds__(1024) void fps_kernel(const float* __restrict__ p,
                                                   float* __restrict__ out) {
#pragma clang fp contract(off)
    const int t = threadIdx.x;
    const int lane = t & 63, wv = t >> 6;
    __shared__ char smem[147456];                      // keys[16384] then s_xy4[1024*9]
    __shared__ float s_pick[1024 * 3];                 // pick ring (12 KB)
    __shared__ ull s_rec[2][16];                       // bare u64 records
    __shared__ float s_recz[2][16];                    // winner-candidate z per wave

    ull* keys = (ull*)smem;
    float4* s_xy4 = (float4*)smem;                     // reuses keys region (144 KB)

    // ---- Phase A: bitonic sort by x (keys unique via idx bits) ----
    for (int u = 0; u < 16; ++u) {
        const int j = u * 1024 + t;
        keys[j] = ((ull)__float_as_uint(p[3 * j]) << 32) | (unsigned)j;
    }
    __syncthreads();
    for (int k = 2; k <= N_PTS; k <<= 1) {
        for (int j = k >> 1; j > 0; j >>= 1) {
            for (int e = 0; e < 8; ++e) {
                const int c = e * 1024 + t;
                const int i1 = 2 * c - (c & (j - 1));
                const int i2 = i1 + j;
                const ull a = keys[i1], b = keys[i2];
                const bool up = ((i1 & k) == 0);
                if ((a > b) == up) { keys[i1] = b; keys[i2] = a; }
            }
            __syncthreads();
        }
    }

    // read own 16 sorted keys -> packed original indices (8 regs)
    unsigned opk[8];
#pragma unroll
    for (int u = 0; u < 8; ++u) {
        const ull a = keys[t * 16 + 2 * u];
        const ull b = keys[t * 16 + 2 * u + 1];
        opk[u] = ((unsigned)a & 0xffffu) | (((unsigned)b & 0xffffu) << 16);
    }
    __syncthreads();                                   // all key reads done before overwrite

    // ---- gather coords: LDS xy ({x0,x1,y0,y1}) + reg z/d2, init bk ----
    v2f zp[8], d2[8];
    unsigned kqx[8], kqy[8];                           // (orig^0x3fff)<<14 | sortpos
    const float q0x = p[0], q0y = p[1], q0z = p[2];
    ull bk = 0;
    float xf = 0.0f, xl = 0.0f;
#pragma unroll
    for (int u = 0; u < 8; ++u) {
        const int o0 = (int)(opk[u] & 0xffffu), o1 = (int)(opk[u] >> 16);
        const float x0 = p[3 * o0], y0 = p[3 * o0 + 1], z0 = p[3 * o0 + 2];
        const float x1 = p[3 * o1], y1 = p[3 * o1 + 1], z1 = p[3 * o1 + 2];
        s_xy4[t * 9 + u] = make_float4(x0, x1, y0, y1);
        zp[u] = (v2f){z0, z1};
        d2[u] = (v2f){dist2_exact(x0, y0, z0, q0x, q0y, q0z),
                      dist2_exact(x1, y1, z1, q0x, q0y, q0z)};
        kqx[u] = ((unsigned)(o0 ^ 0x3fff) << 14) | (unsigned)(t * 16 + 2 * u);
        kqy[u] = ((unsigned)(o1 ^ 0x3fff) << 14) | (unsigned)(t * 16 + 2 * u + 1);
        const ull ka = ((ull)__float_as_uint(d2[u].x) << 32) | (ull)kqx[u];
        const ull kb = ((ull)__float_as_uint(d2[u].y) << 32) | (ull)kqy[u];
        bk = umax64(bk, umax64(ka, kb));
        if (u == 0) xf = x0;
        if (u == 7) xl = x1;
    }
    const float wxmin = __int_as_float(__builtin_amdgcn_readlane(__float_as_int(xf), 0));
    const float wxmax = __int_as_float(__builtin_amdgcn_readlane(__float_as_int(xl), 63));
    const float cx = 0.5f * (wxmin + wxmax);
    const float hw_safe = 0.5f * (wxmax - wxmin) + 1e-5f;

    float my_wval, my_qz;
    unsigned my_klo, my_khi;
    EXTRACT_RECORD();
    if (lane == 0) {
        s_rec[1][wv] = ((ull)my_khi << 32) | (ull)my_klo;
        s_recz[1][wv] = my_qz;
    }
    if (t == 0) { s_pick[0] = q0x; s_pick[1] = q0y; s_pick[2] = q0z; }

    for (int i = 1; i < M_PTS; ++i) {
        const int par = i & 1;
        __syncthreads();                               // the ONE barrier per iteration

        // ring flush: once per 512 iters, previous 512-block (other ring half)
        if ((i & 511) == 0) {
            const int b = (i - 512) & 1023;
            const int base3 = (i - 512) * 3;
            out[base3 + t] = s_pick[b * 3 + t];
            if (t < 512) out[base3 + 1024 + t] = s_pick[b * 3 + 1024 + t];
        }

        // global winner from the 16 records, then uniform broadcast coord fetch
        const int r = lane & 15;
        ull red = s_rec[par][r];
        red = dpp_u64max_step<0x111>(red);
        red = dpp_u64max_step<0x112>(red);
        red = dpp_u64max_step<0x114>(red);
        red = dpp_u64max_step<0x118>(red);
        const unsigned wlo = (unsigned)__builtin_amdgcn_readlane((int)(unsigned)red, 63);
        const unsigned sortpos = wlo & 0x3fffu;
        const int to = (int)(sortpos >> 4), slot = (int)(sortpos & 15u);
        const float qz = s_recz[par][sortpos >> 10];   // record idx = owning wave
        const float4 xy = s_xy4[to * 9 + (slot >> 1)]; // uniform addr -> broadcast
        const float qx = (slot & 1) ? xy.y : xy.x;
        const float qy = (slot & 1) ? xy.w : xy.z;
        if (t == 0) {
            const int s3 = (i & 1023) * 3;
            s_pick[s3] = qx; s_pick[s3 + 1] = qy; s_pick[s3 + 2] = qz;
        }

        // ---- wave-level slab prune: skip update iff provably all no-ops ----
        const float dxq = fabsf(qx - cx);
        bool active = true;
        if (dxq > hw_safe) {
            const float lb = dxq - hw_safe;            // conservative lower bound
            active = (lb * lb <= my_wval);
        }
        if (active) {
            const v2f nqx2 = (v2f){-qx, -qx};
            const v2f nqy2 = (v2f){-qy, -qy};
            const v2f nqz2 = (v2f){-qz, -qz};
            bk = 0;
#pragma unroll
            for (int u = 0; u < 8; ++u) {
                const float4 xyu = s_xy4[t * 9 + u];
                const v2f xp = (v2f){xyu.x, xyu.y};    // {x0,x1}
                const v2f yp = (v2f){xyu.z, xyu.w};    // {y0,y1}
                const v2f dx = pk_add(xp, nqx2);       // exact x - qx
                const v2f dy = pk_add(yp, nqy2);
                const v2f dz = pk_add(zp[u], nqz2);
                const v2f m1 = pk_mul(dx, dx);
                const v2f m2 = pk_mul(dy, dy);
                const v2f m3 = pk_mul(dz, dz);
                const v2f s = pk_add(pk_add(m1, m2), m3);  // ((x²+y²)+z²) exact order
                d2[u] = __builtin_elementwise_min(d2[u], s);
                const ull ka = ((ull)__float_as_uint(d2[u].x) << 32) | (ull)kqx[u];
                const ull kb = ((ull)__float_as_uint(d2[u].y) << 32) | (ull)kqy[u];
                bk = umax64(bk, umax64(ka, kb));
            }
            EXTRACT_RECORD();                          // refresh record (SGPRs)
        }
        if (lane == 0) {
            s_rec[1 - par][wv] = ((ull)my_khi << 32) | (ull)my_klo;
            s_recz[1 - par][wv] = my_qz;
        }
    }

    // final flush: picks 3584..4095 (ring half b=512) + n_o scalar
    __syncthreads();
    {
        const int base3 = 3584 * 3;
        const int b3 = 512 * 3;
        out[base3 + t] = s_pick[b3 + t];
        if (t < 512) out[base3 + 1024 + t] = s_pick[b3 + 1024 + t];
        if (t == 0) out[12288 + 786432] = 4096.0f;
    }
}

// ---------------------------------------------------------------------------
// Kernel 2 (R25): fused knn + vn. knn unchanged (bit-exactness). vn k-split
// as R16, but staging vectorized to float4 (x rows are 768 B-aligned; same
// bytes -> same LDS image -> bit-exact): 6 gather iterations/thread/half
// instead of 24, 4x fewer address divides.
// ---------------------------------------------------------------------------
__global__ __launch_bounds__(1024)
void knnvn_kernel(const float* __restrict__ p, const float* __restrict__ x,
                  const float* __restrict__ Wf, const float* __restrict__ Wd,
                  float* __restrict__ out) {
    __shared__ __align__(16) char SMEM[133120];
    float* sWf = (float*)SMEM;                         // 16 KB  [c*64+o]
    float* sWd = (float*)(SMEM + 16384);               // 16 KB
    float* sg  = (float*)(SMEM + 32768);               // 96 KB  16 q x 8 k x 192
    int*  s_nn = (int*)(SMEM + 131072);                // 1 KB   16 q x 16

    const int t = threadIdx.x;
    const int lane = t & 63, wv = t >> 6;
    const int qbase = (int)blockIdx.x * 16;            // 256 blocks x 16 = 4096

    for (int u = t; u < CIN * COUT; u += 1024) {
        const int o = u >> 6, c = u & 63;
        sWf[c * 64 + o] = Wf[u];
        sWd[c * 64 + o] = Wd[u];
    }

    // ---- knn: one wave per query, results into LDS (exact top_k semantics) ----
    {
        const int m = qbase + wv;
        const float qx = out[3 * m], qy = out[3 * m + 1], qz = out[3 * m + 2];
        const float qq2 = __fadd_rn(__fadd_rn(__fmul_rn(qx, qx), __fmul_rn(qy, qy)),
                                    __fmul_rn(qz, qz));
        float D[16]; int I[16];
#pragma unroll
        for (int s = 0; s < 16; ++s) { D[s] = FLT_MAX; I[s] = 0x7fffffff; }
        for (int c = 0; c < N_PTS / 64; ++c) {
            const int j = c * 64 + lane;
            const float px = p[3 * j], py = p[3 * j + 1], pz = p[3 * j + 2];
            const float pp = __fadd_rn(__fadd_rn(__fmul_rn(px, px), __fmul_rn(py, py)),
                                       __fmul_rn(pz, pz));
            const float qp = __fadd_rn(__fadd_rn(__fmul_rn(qx, px), __fmul_rn(qy, py)),
                                       __fmul_rn(qz, pz));
            const float d = __fadd_rn(__fsub_rn(qq2, __fmul_rn(2.0f, qp)), pp);
            if (d < D[15]) {
                D[15] = d; I[15] = j;
#pragma unroll
                for (int s = 15; s > 0; --s) {
                    if (D[s] < D[s - 1]) {
                        float tf = D[s]; D[s] = D[s - 1]; D[s - 1] = tf;
                        int   ti = I[s]; I[s] = I[s - 1]; I[s - 1] = ti;
                    }
                }
            }
        }
        int myout = 0;
        for (int r = 0; r < 16; ++r) {
            float v = D[0]; int ix = I[0]; int bl = lane;
#pragma unroll
            for (int off = 1; off < 64; off <<= 1) {
                float ov = __shfl_xor(v, off);
                int   oi = __shfl_xor(ix, off);
                int   ol = __shfl_xor(bl, off);
                if (ov < v || (ov == v && oi < ix)) { v = ov; ix = oi; bl = ol; }
            }
            if (lane == bl) {
#pragma unroll
                for (int s = 0; s < 15; ++s) { D[s] = D[s + 1]; I[s] = I[s + 1]; }
                D[15] = FLT_MAX; I[15] = 0x7fffffff;
            }
            if (lane == r) myout = ix;
        }
        if (lane < K_NN) s_nn[wv * K_NN + lane] = myout;
    }

    // ---- vn, k-split: all 1024 threads = (qi 0..15, o 0..63) ----
    const int qi = t >> 6, o = t & 63;
    float a0 = 0.0f, a1 = 0.0f, a2 = 0.0f;
#pragma unroll
    for (int half = 0; half < 2; ++half) {
        __syncthreads();                               // nn ready / sg reuse safe
        // stage k in [half*8, half*8+8) for all 16 queries: 6144 float4s
        for (int idx4 = t; idx4 < 16 * 8 * 48; idx4 += 1024) {
            const int pair = idx4 / 48;                // qj*8 + kk
            const int c4 = idx4 - pair * 48;
            const int jn = s_nn[(pair >> 3) * K_NN + half * 8 + (pair & 7)];
            *(float4*)&sg[pair * 192 + c4 * 4] =
                *(const float4*)&x[jn * 192 + c4 * 4];
        }
        __syncthreads();
        for (int kk = 0; kk < 8; ++kk) {
            const float* gk = &sg[(qi * 8 + kk) * 192];
            float q0 = 0.0f, q1 = 0.0f, q2 = 0.0f;
            float d0 = 0.0f, d1 = 0.0f, d2v = 0.0f;
#pragma unroll 8
            for (int c = 0; c < CIN; ++c) {
                const float wf = sWf[c * 64 + o];
                const float wd = sWd[c * 64 + o];
                const float g0 = gk[c * 3], g1 = gk[c * 3 + 1], g2 = gk[c * 3 + 2];
                q0 = fmaf(wf, g0, q0); q1 = fmaf(wf, g1, q1); q2 = fmaf(wf, g2, q2);
                d0 = fmaf(wd, g0, d0); d1 = fmaf(wd, g1, d1); d2v = fmaf(wd, g2, d2v);
            }
            const float dot = q0 * d0 + q1 * d1 + q2 * d2v;
            const float dns = d0 * d0 + d1 * d1 + d2v * d2v + 1e-6f;
            const float f = (dot >= 0.0f) ? 0.0f : 0.8f * (dot / dns);
            a0 += q0 - f * d0;
            a1 += q1 - f * d1;
            a2 += q2 - f * d2v;
        }
    }
    float* xo = out + 12288;
    const int m = qbase + qi;
    xo[(o * 3 + 0) * M_PTS + m] = a0 * 0.0625f;        // mean over 16
    xo[(o * 3 + 1) * M_PTS + m] = a1 * 0.0625f;
    xo[(o * 3 + 2) * M_PTS + m] = a2 * 0.0625f;
}

// ---------------------------------------------------------------------------
extern "C" void kernel_launch(void* const* d_in, const int* in_sizes, int n_in,
                              void* d_out, int out_size, void* d_ws, size_t ws_size,
                              hipStream_t stream) {
    const float* p  = (const float*)d_in[0];
    const float* x  = (const float*)d_in[1];
    const float* Wf = (const float*)d_in[2];
    const float* Wd = (const float*)d_in[3];
    float* out = (float*)d_out;

    fps_kernel<<<1, 1024, 0, stream>>>(p, out);
    knnvn_kernel<<<256, 1024, 0, stream>>>(p, x, Wf, Wd, out);
}